// Round 1
// baseline (230.157 us; speedup 1.0000x reference)
//
#include <hip/hip_runtime.h>

#define HW_ (1024 * 1024)   // H*W = 2^20, H=W=1024

__global__ __launch_bounds__(256) void ploss_kernel(
        const float* __restrict__ logits,
        const float* __restrict__ image,
        float* __restrict__ out, int total, float scale) {
    int idx = blockIdx.x * 256 + threadIdx.x;
    float acc = 0.0f;
    if (idx < total) {
        int c = idx >> 20;            // idx / HW
        int l = idx & (HW_ - 1);      // idx % HW
        const float* __restrict__ img = image + (size_t)c * HW_;
        const float* __restrict__ lg  = logits + (size_t)c * HW_;

        // r[l,q] = patches[(9l+q)/HW][(9l+q)%HW]  (flat reshape, NOT transpose)
        float rimg[9], rm[9];
        int m0 = l * 9;
        #pragma unroll
        for (int q = 0; q < 9; ++q) {
            int m = m0 + q;
            int pi = m >> 20;             // patch index 0..8
            int si = m & (HW_ - 1);       // spatial flat index
            int i = pi / 3;
            int j = pi - 3 * i;
            int row = (si >> 10) + 2 * i - 2;   // x-row = si_row + 2*(i-1)
            int col = (si & 1023) + 2 * j - 2;  // x-col = si_col + 2*(j-1)
            float iv = 0.0f, mv = 0.0f;         // zero padding (applied AFTER sigmoid)
            if ((unsigned)row < 1024u && (unsigned)col < 1024u) {
                int off = (row << 10) | col;
                iv = img[off];
                mv = 1.0f / (1.0f + __expf(-lg[off]));  // sigmoid
            }
            rimg[q] = iv;
            rm[q]   = mv;
        }

        // node = column 5 (s//2 + 1, reference quirk); edge = cols {0,1,2,3,5,6,7,8}
        float nimg = rimg[5];
        float nm   = rm[5];
        #pragma unroll
        for (int q = 0; q < 9; ++q) {
            if (q == 4) continue;
            float sim  = __expf(-0.5f * fabsf(nimg - rimg[q]));
            float e    = rm[q];
            float prob = e * nm + (1.0f - e) * (1.0f - nm);
            float t    = (sim >= 0.9f) ? __logf(prob) : 0.0f;
            acc -= t;   // -flag*log(prob)
        }
        acc *= scale;   // 1/(n_classes * HW)
    }

    // wave(64) shuffle reduce -> LDS across 4 waves -> one atomicAdd per block
    #pragma unroll
    for (int o = 32; o > 0; o >>= 1) acc += __shfl_down(acc, o, 64);
    __shared__ float sm[4];
    int lane = threadIdx.x & 63;
    int wid  = threadIdx.x >> 6;
    if (lane == 0) sm[wid] = acc;
    __syncthreads();
    if (threadIdx.x == 0) {
        atomicAdd(out, sm[0] + sm[1] + sm[2] + sm[3]);
    }
}

extern "C" void kernel_launch(void* const* d_in, const int* in_sizes, int n_in,
                              void* d_out, int out_size, void* d_ws, size_t ws_size,
                              hipStream_t stream) {
    const float* logits = (const float*)d_in[0];  // inputs (N,1,H,W) fp32
    const float* image  = (const float*)d_in[1];  // image  (N,1,H,W) fp32
    float* out = (float*)d_out;                   // scalar fp32

    int nc = in_sizes[0] / HW_;                   // 4 classes
    int total = nc * HW_;
    float scale = 1.0f / ((float)nc * (float)HW_);

    hipMemsetAsync(out, 0, sizeof(float), stream);
    int blocks = (total + 255) / 256;
    ploss_kernel<<<blocks, 256, 0, stream>>>(logits, image, out, total, scale);
}

// Round 2
// 83.214 us; speedup vs baseline: 2.7658x; 2.7658x over previous
//
#include <hip/hip_runtime.h>

#define HW_   (1024 * 1024)   // H*W = 2^20
#define R_    2               // image rows per block
#define RS_   (R_ + 4)        // staged rows (2-row halo each side)
#define WS_   1028            // staged cols (2-col halo each side)

// st[rr*WS_+cc] = {img, sigmoid(logits)} at (row = r0-2+rr, col = cc-2), 0 if OOB
__global__ __launch_bounds__(256) void ploss2(
        const float* __restrict__ logits_,
        const float* __restrict__ image_,
        float* __restrict__ out, int nwg, float scale) {
    __shared__ float2 st[RS_ * WS_];   // 49.3 KB

    // bijective XCD-chunked swizzle (nwg % 8 == 0): adjacent row-blocks same XCD
    int bid = blockIdx.x;
    int cpx = nwg >> 3;
    int wg  = (bid & 7) * cpx + (bid >> 3);

    int c  = wg >> 9;            // 512 row-blocks per class (R_=2)
    int rb = wg & 511;
    int r0 = rb * R_;
    const float* __restrict__ img = image_  + (size_t)c * HW_;
    const float* __restrict__ lg  = logits_ + (size_t)c * HW_;
    int tid = threadIdx.x;

    // ---- stage (R_+4) x 1028 tile, sigmoid applied, OOB = 0 ----
    for (int rr = 0; rr < RS_; ++rr) {
        int row = r0 - 2 + rr;
        bool rok = (unsigned)row < 1024u;
        const float* gi = img + ((size_t)row << 10);
        const float* gl = lg  + ((size_t)row << 10);
        for (int cc = tid; cc < WS_; cc += 256) {
            int col = cc - 2;
            float iv = 0.0f, mv = 0.0f;
            if (rok && (unsigned)col < 1024u) {
                iv = gi[col];
                mv = 1.0f / (1.0f + __expf(-gl[col]));
            }
            st[rr * WS_ + cc] = make_float2(iv, mv);
        }
    }
    __syncthreads();

    // flag = exp(-0.5|d|) >= 0.9  <=>  |d| <= -2*ln(0.9)
    const float T = 0.21072103131565256f;
    float acc = 0.0f;
    int base = r0 << 10;                 // first si of this block (class-local)
    int si0  = base + tid;
    int q00  = si0 % 9;

    for (int k = 0; k < R_ * 4; ++k) {
        int si = si0 + k * 256;
        int ro = si >> 10, co = si & 1023;
        int rr = ro - r0 + 2;            // 2..3
        int ebase = rr * WS_ + co + 2;   // edge idx = ebase + di*WS_ + dj
        int q = q00;                     // q(pi) = (si + pi*2^20) % 9 ; 2^20 % 9 == 4
        #pragma unroll
        for (int pi = 0; pi < 9; ++pi) {
            const int di = 2 * (pi / 3) - 2, dj = 2 * (pi % 3) - 2;
            if (q != 4) {
                float2 e = st[ebase + di * WS_ + dj];
                int sn = si + 5 - q;     // node spatial index (same pi, usually)
                float2 n;
                int rrn = (sn >> 10) - r0 + 2 + di;
                if ((unsigned)sn < (unsigned)HW_ && (unsigned)rrn < (unsigned)RS_) {
                    n = st[rrn * WS_ + (sn & 1023) + 2 + dj];
                } else {
                    // rare: node crosses 2^20 boundary (different pi) or staged rows
                    int mn  = pi * HW_ + sn;          // = 9*l + 5, in [5, 9*2^20)
                    int pin = mn >> 20, sin = mn & (HW_ - 1);
                    int din = 2 * (pin / 3) - 2, djn = 2 * (pin % 3) - 2;
                    int rn = (sin >> 10) + din, cn = (sin & 1023) + djn;
                    n = make_float2(0.0f, 0.0f);
                    if ((unsigned)rn < 1024u && (unsigned)cn < 1024u) {
                        int off = (rn << 10) | cn;
                        n.x = img[off];
                        n.y = 1.0f / (1.0f + __expf(-lg[off]));
                    }
                }
                if (fabsf(n.x - e.x) <= T) {
                    float prob = e.y * n.y + (1.0f - e.y) * (1.0f - n.y);
                    acc -= __logf(prob);
                }
            }
            q += 4; if (q >= 9) q -= 9;
        }
        q00 += 4; if (q00 >= 9) q00 -= 9;   // 256 % 9 == 4
    }
    acc *= scale;

    // wave shuffle reduce -> LDS across 4 waves -> one atomicAdd per block
    #pragma unroll
    for (int o = 32; o > 0; o >>= 1) acc += __shfl_down(acc, o, 64);
    __shared__ float sm[4];
    int lane = tid & 63, wid = tid >> 6;
    if (lane == 0) sm[wid] = acc;
    __syncthreads();
    if (tid == 0) atomicAdd(out, sm[0] + sm[1] + sm[2] + sm[3]);
}

extern "C" void kernel_launch(void* const* d_in, const int* in_sizes, int n_in,
                              void* d_out, int out_size, void* d_ws, size_t ws_size,
                              hipStream_t stream) {
    const float* logits = (const float*)d_in[0];  // inputs (N,1,H,W) fp32
    const float* image  = (const float*)d_in[1];  // image  (N,1,H,W) fp32
    float* out = (float*)d_out;

    int nc   = in_sizes[0] / HW_;                 // 4 classes
    int nwg  = nc * (1024 / R_);                  // 2048 blocks
    float scale = 1.0f / ((float)nc * (float)HW_);

    hipMemsetAsync(out, 0, sizeof(float), stream);
    ploss2<<<nwg, 256, 0, stream>>>(logits, image, out, nwg, scale);
}